// Round 4
// baseline (147.520 us; speedup 1.0000x reference)
//
#include <hip/hip_runtime.h>
#include <math.h>

#define NB 2
#define NH 8
#define SS 160
#define DD 64
#define NT 640

typedef __attribute__((ext_vector_type(8))) short bf16x8;
typedef __attribute__((ext_vector_type(4))) float f32x4;

// split a pair of fp32 into packed bf16 (hi, lo); lo captures the residual.
__device__ __forceinline__ uint2 splitpair(float a0, float a1) {
    unsigned u0 = __float_as_uint(a0), u1 = __float_as_uint(a1);
    unsigned hi = (u0 >> 16) | (u1 & 0xffff0000u);
    float r0 = a0 - __uint_as_float(u0 & 0xffff0000u);
    float r1 = a1 - __uint_as_float(u1 & 0xffff0000u);
    unsigned v0 = __float_as_uint(r0), v1 = __float_as_uint(r1);
    unsigned lo = (v0 >> 16) | (v1 & 0xffff0000u);
    return make_uint2(hi, lo);
}

// LDS: 4 arrays of [160 rows][8 groups of 8 bf16] (20480 B each):
//   A_hi @0, A_lo @20480, B_hi @40960, B_lo @61440.  Group g of row s lives
//   at slot g^(s&7): staging stores and fragment reads are both conflict-free
//   (measured 0 SQ_LDS_BANK_CONFLICT in R2) and tile offsets are immediates.
__global__ __launch_bounds__(NT, 5) void tritt_kernel(
    const float* __restrict__ q,  const float* __restrict__ k1,
    const float* __restrict__ k2, const float* __restrict__ v1,
    const float* __restrict__ v2, float* __restrict__ out)
{
    __shared__ __align__(16) char sm[81920];   // 80 KB -> 2 blocks/CU, 20 waves

    const int tid = threadIdx.x;
    const int blk = blockIdx.x;
    const int bh  = blk / SS;
    const int qi  = blk % SS;
    const size_t base = (size_t)bh * SS * DD;

    const float4* k1f = (const float4*)(k1 + base);
    const float4* k2f = (const float4*)(k2 + base);
    const float4* qf  = (const float4*)(q + base + (size_t)qi * DD);

    // ---- stage: A = q ⊙ k1 and B = k2, split to bf16 hi/lo in LDS ----
    #pragma unroll
    for (int it = 0; it < 2; ++it) {
        int f = tid + NT * it;            // 0..1279 = 160 rows x 8 groups
        int s = f >> 3, g = f & 7;
        int fg = s * 16 + g * 2;          // float4 index of 8-float group
        float4 x0 = k1f[fg], x1 = k1f[fg + 1];
        float4 y0 = k2f[fg], y1 = k2f[fg + 1];
        float4 q0 = qf[g * 2], q1 = qf[g * 2 + 1];

        uint2 pa0 = splitpair(x0.x * q0.x, x0.y * q0.y);
        uint2 pa1 = splitpair(x0.z * q0.z, x0.w * q0.w);
        uint2 pa2 = splitpair(x1.x * q1.x, x1.y * q1.y);
        uint2 pa3 = splitpair(x1.z * q1.z, x1.w * q1.w);
        uint2 pb0 = splitpair(y0.x, y0.y);
        uint2 pb1 = splitpair(y0.z, y0.w);
        uint2 pb2 = splitpair(y1.x, y1.y);
        uint2 pb3 = splitpair(y1.z, y1.w);

        int off = s * 128 + ((g ^ (s & 7)) * 16);
        *(uint4*)(sm + off)         = make_uint4(pa0.x, pa1.x, pa2.x, pa3.x);
        *(uint4*)(sm + 20480 + off) = make_uint4(pa0.y, pa1.y, pa2.y, pa3.y);
        *(uint4*)(sm + 40960 + off) = make_uint4(pb0.x, pb1.x, pb2.x, pb3.x);
        *(uint4*)(sm + 61440 + off) = make_uint4(pb0.y, pb1.y, pb2.y, pb3.y);
    }
    __syncthreads();

    // ---- MFMA: wave w=(wy,wx), wy=w>>1 in[0,5), wx=w&1: s in [32wy,+32),
    //      t in [80wx,+80). acc[2][5] 16x16 tiles ----
    const int lane = tid & 63;
    const int wid  = tid >> 6;             // 0..9
    const int wy = wid >> 1, wx = wid & 1;
    const int s0 = 32 * wy, t0 = 80 * wx;
    const int n16 = lane & 15, quad = lane >> 4;

    f32x4 acc[2][5];
    #pragma unroll
    for (int i = 0; i < 2; ++i)
        #pragma unroll
        for (int j = 0; j < 5; ++j) acc[i][j] = (f32x4){0.f, 0.f, 0.f, 0.f};

    #pragma unroll
    for (int ks = 0; ks < 2; ++ks) {
        const int sg = (4 * ks + quad) ^ (n16 & 7);   // swizzled group slot
        const char* abase = sm + (s0 + n16) * 128 + sg * 16;
        const char* bbase = sm + 40960 + (t0 + n16) * 128 + sg * 16;
        bf16x8 ah[2], al[2];
        #pragma unroll
        for (int i = 0; i < 2; ++i) {
            ah[i] = *(const bf16x8*)(abase + 2048 * i);
            al[i] = *(const bf16x8*)(abase + 20480 + 2048 * i);
        }
        #pragma unroll
        for (int j = 0; j < 5; ++j) {
            bf16x8 bh8 = *(const bf16x8*)(bbase + 2048 * j);
            bf16x8 bl8 = *(const bf16x8*)(bbase + 20480 + 2048 * j);
            #pragma unroll
            for (int i = 0; i < 2; ++i) {
                acc[i][j] = __builtin_amdgcn_mfma_f32_16x16x32_bf16(ah[i], bh8, acc[i][j], 0, 0, 0);
                acc[i][j] = __builtin_amdgcn_mfma_f32_16x16x32_bf16(al[i], bh8, acc[i][j], 0, 0, 0);
                acc[i][j] = __builtin_amdgcn_mfma_f32_16x16x32_bf16(ah[i], bl8, acc[i][j], 0, 0, 0);
            }
        }
    }
    __syncthreads();   // staging LDS dead; alias reduction arrays

    float* A1    = (float*)sm;          // [160] row sums (over t)
    float* A2    = A1 + SS;             // [160] col sums (over s)
    float* wredm = A2 + SS;             // [10] wave maxes
    float* wreds = wredm + 10;          // [10] wave sums
    float* zred  = wreds + 10;          // [640] gemv partials

    if (tid < SS) { A1[tid] = 0.f; A2[tid] = 0.f; }

    // ---- block max (acc touch #1) ----
    float mloc = -1e30f;
    #pragma unroll
    for (int i = 0; i < 2; ++i)
        #pragma unroll
        for (int j = 0; j < 5; ++j)
            #pragma unroll
            for (int r = 0; r < 4; ++r) mloc = fmaxf(mloc, acc[i][j][r]);
    #pragma unroll
    for (int off = 32; off; off >>= 1) mloc = fmaxf(mloc, __shfl_xor(mloc, off, 64));
    if (lane == 0) wredm[wid] = mloc;
    __syncthreads();
    float m = wredm[0];
    #pragma unroll
    for (int w = 1; w < 10; ++w) m = fmaxf(m, wredm[w]);

    // ---- exp + fused marginals (acc touch #2; exp never written back) ----
    float rs[2][4];
    float cs[5];
    #pragma unroll
    for (int i = 0; i < 2; ++i)
        #pragma unroll
        for (int r = 0; r < 4; ++r) rs[i][r] = 0.f;
    #pragma unroll
    for (int j = 0; j < 5; ++j) cs[j] = 0.f;
    float lsum = 0.f;
    #pragma unroll
    for (int i = 0; i < 2; ++i)
        #pragma unroll
        for (int j = 0; j < 5; ++j)
            #pragma unroll
            for (int r = 0; r < 4; ++r) {
                float e = __expf(acc[i][j][r] - m);
                lsum += e;
                rs[i][r] += e;
                cs[j] += e;
            }
    #pragma unroll
    for (int off = 32; off; off >>= 1) lsum += __shfl_xor(lsum, off, 64);
    if (lane == 0) wreds[wid] = lsum;

    // row sums: s = s0 + 16i + 4*quad + r; reduce over the 16 n-lanes
    #pragma unroll
    for (int i = 0; i < 2; ++i)
        #pragma unroll
        for (int r = 0; r < 4; ++r) {
            float v = rs[i][r];
            v += __shfl_xor(v, 1, 64); v += __shfl_xor(v, 2, 64);
            v += __shfl_xor(v, 4, 64); v += __shfl_xor(v, 8, 64);
            if (n16 == 0) atomicAdd(&A1[s0 + 16 * i + 4 * quad + r], v);
        }
    // col sums: t = t0 + 16j + n16; reduce over quad
    #pragma unroll
    for (int j = 0; j < 5; ++j) {
        float v = cs[j];
        v += __shfl_xor(v, 16, 64);
        v += __shfl_xor(v, 32, 64);
        if (quad == 0) atomicAdd(&A2[t0 + 16 * j + n16], v);
    }
    __syncthreads();

    float l = wreds[0];
    #pragma unroll
    for (int w = 1; w < 10; ++w) l += wreds[w];
    if (tid == 0)
        out[(size_t)NB * NH * SS * DD + (size_t)bh * SS + qi] = m + __logf(l);

    // ---- z[q,d] = (A1 @ v1 + A2 @ v2) / l ----
    const int d    = tid & 63;
    const int part = tid >> 6;              // 0..9, 16 rows each
    const float* v1p = v1 + base;
    const float* v2p = v2 + base;
    float z = 0.f;
    #pragma unroll 4
    for (int s = part * 16; s < part * 16 + 16; ++s)
        z = fmaf(A1[s], v1p[s * DD + d], fmaf(A2[s], v2p[s * DD + d], z));
    zred[tid] = z;
    __syncthreads();
    if (tid < DD) {
        float zz = 0.f;
        #pragma unroll
        for (int p = 0; p < 10; ++p) zz += zred[tid + 64 * p];
        out[((size_t)bh * SS + qi) * DD + tid] = zz / l;
    }
}

extern "C" void kernel_launch(void* const* d_in, const int* in_sizes, int n_in,
                              void* d_out, int out_size, void* d_ws, size_t ws_size,
                              hipStream_t stream) {
    const float* q  = (const float*)d_in[0];
    const float* k1 = (const float*)d_in[1];
    const float* k2 = (const float*)d_in[2];
    const float* v1 = (const float*)d_in[3];
    const float* v2 = (const float*)d_in[4];
    float* out = (float*)d_out;
    tritt_kernel<<<dim3(NB * NH * SS), dim3(NT), 0, stream>>>(q, k1, k2, v1, v2, out);
}

// Round 5
// 145.152 us; speedup vs baseline: 1.0163x; 1.0163x over previous
//
#include <hip/hip_runtime.h>
#include <math.h>

#define NB 2
#define NH 8
#define BHN 16
#define SS 160
#define DD 64

typedef __attribute__((ext_vector_type(8))) short bf16x8;
typedef __attribute__((ext_vector_type(4))) float f32x4;

// split a pair of fp32 into packed bf16 (hi, lo); lo captures the residual.
__device__ __forceinline__ uint2 splitpair(float a0, float a1) {
    unsigned u0 = __float_as_uint(a0), u1 = __float_as_uint(a1);
    unsigned hi = (u0 >> 16) | (u1 & 0xffff0000u);
    float r0 = a0 - __uint_as_float(u0 & 0xffff0000u);
    float r1 = a1 - __uint_as_float(u1 & 0xffff0000u);
    unsigned v0 = __float_as_uint(r0), v1 = __float_as_uint(r1);
    unsigned lo = (v0 >> 16) | (v1 & 0xffff0000u);
    return make_uint2(hi, lo);
}

// ============================ PHASE 1 ============================
// Block = (bh, q-chunk of 32, s-chunk of 32). grid = 16*5*5 = 400.
// Per fixed s: scores[q32, t160] = (Q ⊙ k1[s,:]) x k2^T via 16x16x32 bf16
// MFMA, 3-term hi/lo. k2 fragments are s-invariant: Bh kept in registers,
// Bl read from LDS. A2[q,t] accumulates in registers over s (exclusive
// partial per block -> ws). A1[q,s] reduced per s into LDS (exclusive ->
// global). m=0 softmax: store raw exp-sums; lse = log(sum) in phase 2.
// LDS 52 KB -> 3 blocks/CU (12 waves).
__global__ __launch_bounds__(256, 3) void tritt_p1(
    const float* __restrict__ q,  const float* __restrict__ k1,
    const float* __restrict__ k2, float* __restrict__ A1g,
    float* __restrict__ A2p)
{
    __shared__ __align__(16) char sm[53248];
    // k2h bf16 [160][8 blk][16B] @0 ; k2l @20480 ; k1 f32 [32][64] @40960 ;
    // A1buf f32 [32 s][32 q] @49152
    char*  k2hB  = sm;
    char*  k2lB  = sm + 20480;
    float* k1buf = (float*)(sm + 40960);
    float* A1buf = (float*)(sm + 49152);

    const int tid = threadIdx.x;
    const int blk = blockIdx.x;
    const int bh  = blk / 25;
    const int rem = blk % 25;
    const int qc  = rem / 5, sc = rem % 5;
    const size_t base = (size_t)bh * SS * DD;

    // ---- stage k2 (all 160 t) as hi/lo bf16, 16B-block swizzled by t&7 ----
    const float4* k2f = (const float4*)(k2 + base);
    #pragma unroll
    for (int it = 0; it < 5; ++it) {
        int f = tid + 256 * it;          // 0..1279: t = f>>3, 16B-block o = f&7
        int t = f >> 3, o = f & 7;
        float4 x0 = k2f[t * 16 + 2 * o];
        float4 x1 = k2f[t * 16 + 2 * o + 1];
        uint2 p0 = splitpair(x0.x, x0.y);
        uint2 p1 = splitpair(x0.z, x0.w);
        uint2 p2 = splitpair(x1.x, x1.y);
        uint2 p3 = splitpair(x1.z, x1.w);
        int off = t * 128 + ((o ^ (t & 7)) * 16);
        *(uint4*)(k2hB + off) = make_uint4(p0.x, p1.x, p2.x, p3.x);
        *(uint4*)(k2lB + off) = make_uint4(p0.y, p1.y, p2.y, p3.y);
    }
    // ---- stage k1 chunk (fp32, linear; read via broadcast later) ----
    {
        const float4* k1f = (const float4*)(k1 + base) + sc * 512;
        float4* dst = (float4*)k1buf;
        dst[tid]       = k1f[tid];
        dst[tid + 256] = k1f[tid + 256];
    }
    ((float4*)A1buf)[tid] = (float4){0.f, 0.f, 0.f, 0.f};

    // ---- per-wave constants: wave (mt, nh) owns q16-tile mt, t-half nh ----
    const int lane = tid & 63, wid = tid >> 6;
    const int mt = wid & 1, nh = wid >> 1;
    const int n16 = lane & 15, quad = lane >> 4;

    // Q rows (fp32, registers): lane n16 -> q row, quad -> h-octet
    const float* qrow = q + base + (size_t)(qc * 32 + mt * 16 + n16) * DD + quad * 8;
    float Qf[2][8];
    #pragma unroll
    for (int ks = 0; ks < 2; ++ks) {
        float4 a = *(const float4*)(qrow + 32 * ks);
        float4 b = *(const float4*)(qrow + 32 * ks + 4);
        Qf[ks][0] = a.x; Qf[ks][1] = a.y; Qf[ks][2] = a.z; Qf[ks][3] = a.w;
        Qf[ks][4] = b.x; Qf[ks][5] = b.y; Qf[ks][6] = b.z; Qf[ks][7] = b.w;
    }
    __syncthreads();

    // ---- hoist all Bh fragments into registers (s-invariant) ----
    const int trow = nh * 80 + n16;            // t = trow + 16j
    const int swz  = n16 & 7;
    const char* bb0 = k2hB + trow * 128 + ((quad) ^ swz) * 16;       // ks=0
    const char* bb1 = k2hB + trow * 128 + ((4 + quad) ^ swz) * 16;   // ks=1
    const char* lb0 = k2lB + trow * 128 + ((quad) ^ swz) * 16;
    const char* lb1 = k2lB + trow * 128 + ((4 + quad) ^ swz) * 16;
    bf16x8 BH0[5], BH1[5];
    #pragma unroll
    for (int j = 0; j < 5; ++j) {
        BH0[j] = *(const bf16x8*)(bb0 + 2048 * j);
        BH1[j] = *(const bf16x8*)(bb1 + 2048 * j);
    }

    f32x4 A2acc[5];
    #pragma unroll
    for (int j = 0; j < 5; ++j) A2acc[j] = (f32x4){0.f, 0.f, 0.f, 0.f};
    const f32x4 zero4 = (f32x4){0.f, 0.f, 0.f, 0.f};

    // ---- s-loop: build A = Q ⊙ k1[s,:], 30 MFMAs, exp, accumulate ----
    #pragma unroll 2
    for (int s = 0; s < 32; ++s) {
        const float* k1row = k1buf + s * 64 + quad * 8;
        uint4 AH[2], AL[2];
        #pragma unroll
        for (int ks = 0; ks < 2; ++ks) {
            float4 a = *(const float4*)(k1row + 32 * ks);
            float4 b = *(const float4*)(k1row + 32 * ks + 4);
            uint2 p0 = splitpair(Qf[ks][0] * a.x, Qf[ks][1] * a.y);
            uint2 p1 = splitpair(Qf[ks][2] * a.z, Qf[ks][3] * a.w);
            uint2 p2 = splitpair(Qf[ks][4] * b.x, Qf[ks][5] * b.y);
            uint2 p3 = splitpair(Qf[ks][6] * b.z, Qf[ks][7] * b.w);
            AH[ks] = make_uint4(p0.x, p1.x, p2.x, p3.x);
            AL[ks] = make_uint4(p0.y, p1.y, p2.y, p3.y);
        }
        bf16x8 ah0 = *(bf16x8*)&AH[0], al0 = *(bf16x8*)&AL[0];
        bf16x8 ah1 = *(bf16x8*)&AH[1], al1 = *(bf16x8*)&AL[1];

        float rsum[4] = {0.f, 0.f, 0.f, 0.f};
        #pragma unroll
        for (int j = 0; j < 5; ++j) {
            bf16x8 bl0 = *(const bf16x8*)(lb0 + 2048 * j);
            bf16x8 bl1 = *(const bf16x8*)(lb1 + 2048 * j);
            f32x4 a = __builtin_amdgcn_mfma_f32_16x16x32_bf16(ah0, BH0[j], zero4, 0, 0, 0);
            a = __builtin_amdgcn_mfma_f32_16x16x32_bf16(al0, BH0[j], a, 0, 0, 0);
            a = __builtin_amdgcn_mfma_f32_16x16x32_bf16(ah0, bl0,    a, 0, 0, 0);
            a = __builtin_amdgcn_mfma_f32_16x16x32_bf16(ah1, BH1[j], a, 0, 0, 0);
            a = __builtin_amdgcn_mfma_f32_16x16x32_bf16(al1, BH1[j], a, 0, 0, 0);
            a = __builtin_amdgcn_mfma_f32_16x16x32_bf16(ah1, bl1,    a, 0, 0, 0);
            #pragma unroll
            for (int r = 0; r < 4; ++r) {
                float e = __expf(a[r]);
                A2acc[j][r] += e;
                rsum[r] += e;
            }
        }
        // A1[q,s] partial: reduce over the 16 n-lanes (t within tiles)
        #pragma unroll
        for (int r = 0; r < 4; ++r) {
            float v = rsum[r];
            v += __shfl_xor(v, 1, 64); v += __shfl_xor(v, 2, 64);
            v += __shfl_xor(v, 4, 64); v += __shfl_xor(v, 8, 64);
            if (n16 == 0)
                atomicAdd(&A1buf[s * 32 + mt * 16 + quad * 4 + r], v);
        }
    }
    __syncthreads();

    // ---- write A1 (exclusive (bh,qc,sc) slice) ----
    {
        int qi = tid >> 3, si = (tid & 7) * 4;
        float4 w;
        w.x = A1buf[(si + 0) * 32 + qi];
        w.y = A1buf[(si + 1) * 32 + qi];
        w.z = A1buf[(si + 2) * 32 + qi];
        w.w = A1buf[(si + 3) * 32 + qi];
        *(float4*)(A1g + (size_t)bh * 25600 + (qc * 32 + qi) * 160 + sc * 32 + si) = w;
    }
    // ---- write A2 partial (exclusive per-block slot) ----
    {
        float* pb = A2p + (size_t)blk * 5120;   // blk == (bh*5+qc)*5+sc
        #pragma unroll
        for (int j = 0; j < 5; ++j)
            #pragma unroll
            for (int r = 0; r < 4; ++r)
                pb[(mt * 16 + quad * 4 + r) * 160 + nh * 80 + j * 16 + n16] = A2acc[j][r];
    }
}

// ============================ PHASE 2 ============================
// grid 320 = 16 bh x 20 q-groups(8). Thread (d, qsub) handles 2 q's:
// z[q,d] = (sum_s A1 v1 + sum_t (Σ_sc A2p) v2) / l ; lse = log(l).
__global__ __launch_bounds__(256, 4) void tritt_p2(
    const float* __restrict__ v1, const float* __restrict__ v2,
    const float* __restrict__ A1g, const float* __restrict__ A2p,
    float* __restrict__ out)
{
    const int tid = threadIdx.x;
    const int blk = blockIdx.x;
    const int bh = blk / 20, qg = blk % 20;
    const int d = tid & 63, qsub = tid >> 6;      // 2 q per thread
    const int q0 = qg * 8 + qsub * 2;
    const size_t base = (size_t)bh * SS * DD;
    const float* a1 = A1g + (size_t)bh * 25600 + (size_t)q0 * 160;
    const int qc = q0 >> 5, qr0 = q0 & 31;
    const float* a2 = A2p + (size_t)((bh * 5 + qc) * 5) * 5120 + (size_t)qr0 * 160;

    float z[2] = {0.f, 0.f}, l[2] = {0.f, 0.f};
    for (int s = 0; s < SS; ++s) {
        float vv = v1[base + s * 64 + d];
        #pragma unroll
        for (int k = 0; k < 2; ++k) {
            float w = a1[k * 160 + s];
            l[k] += w;
            z[k] = fmaf(w, vv, z[k]);
        }
    }
    for (int t4 = 0; t4 < 40; ++t4) {
        int t = t4 * 4;
        float4 w[2];
        #pragma unroll
        for (int k = 0; k < 2; ++k) {
            const float* p = a2 + k * 160 + t;
            float4 w0 = *(const float4*)(p);
            float4 w1 = *(const float4*)(p + 5120);
            float4 w2 = *(const float4*)(p + 2 * 5120);
            float4 w3 = *(const float4*)(p + 3 * 5120);
            float4 w4 = *(const float4*)(p + 4 * 5120);
            w[k].x = ((w0.x + w1.x) + (w2.x + w3.x)) + w4.x;
            w[k].y = ((w0.y + w1.y) + (w2.y + w3.y)) + w4.y;
            w[k].z = ((w0.z + w1.z) + (w2.z + w3.z)) + w4.z;
            w[k].w = ((w0.w + w1.w) + (w2.w + w3.w)) + w4.w;
        }
        #pragma unroll
        for (int tt = 0; tt < 4; ++tt) {
            float vv = v2[base + (size_t)(t + tt) * 64 + d];
            z[0] = fmaf(((const float*)&w[0])[tt], vv, z[0]);
            z[1] = fmaf(((const float*)&w[1])[tt], vv, z[1]);
        }
    }
    #pragma unroll
    for (int k = 0; k < 2; ++k)
        out[base + (size_t)(q0 + k) * 64 + d] = z[k] / l[k];
    if (d == 0) {
        #pragma unroll
        for (int k = 0; k < 2; ++k)
            out[(size_t)BHN * SS * DD + bh * SS + q0 + k] = __logf(l[k]);
    }
}

// ==================== FALLBACK (proven R2, ~74us) ====================
__device__ __forceinline__ int chunk_idx_fb(int c, int s) {
    return c * SS + ((s & ~15) | ((s ^ c) & 15));
}

__global__ __launch_bounds__(256, 2) void tritt_fb(
    const float* __restrict__ q,  const float* __restrict__ k1,
    const float* __restrict__ k2, const float* __restrict__ v1,
    const float* __restrict__ v2, float* __restrict__ out)
{
    __shared__ __align__(16) char sm[81920];
    const int tid = threadIdx.x;
    const int blk = blockIdx.x;
    const int bh  = blk / SS;
    const int qi  = blk % SS;
    const size_t base = (size_t)bh * SS * DD;

    const float4* k1f = (const float4*)(k1 + base);
    const float4* k2f = (const float4*)(k2 + base);
    const float4* qf  = (const float4*)(q + base + (size_t)qi * DD);

    #pragma unroll
    for (int it = 0; it < 5; ++it) {
        int f = tid + 256 * it;
        int s = f >> 3, g = f & 7;
        int fg = s * 16 + g * 2;
        float4 x0 = k1f[fg], x1 = k1f[fg + 1];
        float4 y0 = k2f[fg], y1 = k2f[fg + 1];
        float4 q0 = qf[g * 2], q1 = qf[g * 2 + 1];
        uint2 pa0 = splitpair(x0.x * q0.x, x0.y * q0.y);
        uint2 pa1 = splitpair(x0.z * q0.z, x0.w * q0.w);
        uint2 pa2 = splitpair(x1.x * q1.x, x1.y * q1.y);
        uint2 pa3 = splitpair(x1.z * q1.z, x1.w * q1.w);
        uint2 pb0 = splitpair(y0.x, y0.y);
        uint2 pb1 = splitpair(y0.z, y0.w);
        uint2 pb2 = splitpair(y1.x, y1.y);
        uint2 pb3 = splitpair(y1.z, y1.w);
        int off = s * 128 + ((g ^ (s & 7)) * 16);
        *(uint4*)(sm + off)         = make_uint4(pa0.x, pa1.x, pa2.x, pa3.x);
        *(uint4*)(sm + 20480 + off) = make_uint4(pa0.y, pa1.y, pa2.y, pa3.y);
        *(uint4*)(sm + 40960 + off) = make_uint4(pb0.x, pb1.x, pb2.x, pb3.x);
        *(uint4*)(sm + 61440 + off) = make_uint4(pb0.y, pb1.y, pb2.y, pb3.y);
    }
    __syncthreads();

    const int lane = tid & 63;
    const int wid  = tid >> 6;
    const int wy = wid >> 1, wx = wid & 1;
    const int s0 = 80 * wy, t0 = 80 * wx;
    const int n16 = lane & 15, quad = lane >> 4, l7 = lane & 7;

    f32x4 acc[5][5];
    #pragma unroll
    for (int i = 0; i < 5; ++i)
        #pragma unroll
        for (int j = 0; j < 5; ++j) acc[i][j] = (f32x4){0.f, 0.f, 0.f, 0.f};

    #pragma unroll 1
    for (int ks = 0; ks < 2; ++ks) {
        const int sg = (4 * ks + quad) ^ l7;
        const char* abase = sm + (s0 + n16) * 128 + sg * 16;
        const char* bbase = sm + 40960 + (t0 + n16) * 128 + sg * 16;
        bf16x8 ah[5], al[5];
        #pragma unroll
        for (int i = 0; i < 5; ++i) {
            ah[i] = *(const bf16x8*)(abase + 2048 * i);
            al[i] = *(const bf16x8*)(abase + 20480 + 2048 * i);
        }
        #pragma unroll
        for (int j = 0; j < 5; ++j) {
            bf16x8 bh8 = *(const bf16x8*)(bbase + 2048 * j);
            bf16x8 bl8 = *(const bf16x8*)(bbase + 20480 + 2048 * j);
            #pragma unroll
            for (int i = 0; i < 5; ++i) {
                acc[i][j] = __builtin_amdgcn_mfma_f32_16x16x32_bf16(ah[i], bh8, acc[i][j], 0, 0, 0);
                acc[i][j] = __builtin_amdgcn_mfma_f32_16x16x32_bf16(al[i], bh8, acc[i][j], 0, 0, 0);
                acc[i][j] = __builtin_amdgcn_mfma_f32_16x16x32_bf16(ah[i], bl8, acc[i][j], 0, 0, 0);
            }
        }
    }
    __syncthreads();

    float* A1   = (float*)sm;
    float* A2   = A1 + SS;
    float* wred = A2 + SS;
    float* zred = wred + 8;

    if (tid < SS) { A1[tid] = 0.f; A2[tid] = 0.f; }

    float mloc = -1e30f;
    #pragma unroll
    for (int i = 0; i < 5; ++i)
        #pragma unroll
        for (int j = 0; j < 5; ++j)
            #pragma unroll
            for (int r = 0; r < 4; ++r) mloc = fmaxf(mloc, acc[i][j][r]);
    #pragma unroll
    for (int off = 32; off; off >>= 1) mloc = fmaxf(mloc, __shfl_xor(mloc, off, 64));
    if (lane == 0) wred[wid] = mloc;
    __syncthreads();
    const float m = fmaxf(fmaxf(wred[0], wred[1]), fmaxf(wred[2], wred[3]));

    float lsum = 0.f;
    #pragma unroll
    for (int i = 0; i < 5; ++i)
        #pragma unroll
        for (int j = 0; j < 5; ++j)
            #pragma unroll
            for (int r = 0; r < 4; ++r) {
                float e = __expf(acc[i][j][r] - m);
                acc[i][j][r] = e;
                lsum += e;
            }
    #pragma unroll
    for (int off = 32; off; off >>= 1) lsum += __shfl_xor(lsum, off, 64);
    if (lane == 0) wred[4 + wid] = lsum;

    #pragma unroll
    for (int i = 0; i < 5; ++i)
        #pragma unroll
        for (int r = 0; r < 4; ++r) {
            float rsv = 0.f;
            #pragma unroll
            for (int j = 0; j < 5; ++j) rsv += acc[i][j][r];
            rsv += __shfl_xor(rsv, 1, 64); rsv += __shfl_xor(rsv, 2, 64);
            rsv += __shfl_xor(rsv, 4, 64); rsv += __shfl_xor(rsv, 8, 64);
            if (n16 == 0) atomicAdd(&A1[s0 + 16 * i + 4 * quad + r], rsv);
        }
    #pragma unroll
    for (int j = 0; j < 5; ++j) {
        float csv = 0.f;
        #pragma unroll
        for (int i = 0; i < 5; ++i)
            #pragma unroll
            for (int r = 0; r < 4; ++r) csv += acc[i][j][r];
        csv += __shfl_xor(csv, 16, 64);
        csv += __shfl_xor(csv, 32, 64);
        if (quad == 0) atomicAdd(&A2[t0 + 16 * j + n16], csv);
    }
    __syncthreads();

    const float l = (wred[4] + wred[5]) + (wred[6] + wred[7]);
    if (tid == 0)
        out[(size_t)NB * NH * SS * DD + (size_t)bh * SS + qi] = m + __logf(l);

    const int d    = tid & 63;
    const int part = tid >> 6;
    const float* v1p = v1 + base;
    const float* v2p = v2 + base;
    float z = 0.f;
    #pragma unroll 4
    for (int s = part * 40; s < part * 40 + 40; ++s)
        z = fmaf(A1[s], v1p[s * DD + d], fmaf(A2[s], v2p[s * DD + d], z));
    zred[tid] = z;
    __syncthreads();
    if (tid < DD) {
        float zz = (zred[tid] + zred[tid + 64]) + (zred[tid + 128] + zred[tid + 192]);
        out[((size_t)bh * SS + qi) * DD + tid] = zz / l;
    }
}

extern "C" void kernel_launch(void* const* d_in, const int* in_sizes, int n_in,
                              void* d_out, int out_size, void* d_ws, size_t ws_size,
                              hipStream_t stream) {
    const float* q  = (const float*)d_in[0];
    const float* k1 = (const float*)d_in[1];
    const float* k2 = (const float*)d_in[2];
    const float* v1 = (const float*)d_in[3];
    const float* v2 = (const float*)d_in[4];
    float* out = (float*)d_out;

    const size_t REQ = (size_t)(409600 + 400 * 5120) * sizeof(float); // 9.83 MB
    if (ws_size >= REQ) {
        float* A1g = (float*)d_ws;
        float* A2p = A1g + 409600;
        tritt_p1<<<dim3(400), dim3(256), 0, stream>>>(q, k1, k2, A1g, A2p);
        tritt_p2<<<dim3(320), dim3(256), 0, stream>>>(v1, v2, A1g, A2p, out);
    } else {
        tritt_fb<<<dim3(NB * NH * SS), dim3(256), 0, stream>>>(q, k1, k2, v1, v2, out);
    }
}